// Round 2
// baseline (354.967 us; speedup 1.0000x reference)
//
#include <hip/hip_runtime.h>
#include <hip/hip_bf16.h>

using bf16 = __hip_bfloat16;

static constexpr int N  = 2;
static constexpr int C  = 64;     // inC
static constexpr int H  = 256;
static constexpr int W  = 256;
static constexpr int Hd = 128;
static constexpr int Wd = 128;
static constexpr int Cm = 64;     // mid channels
static constexpr int KK = 25;     // K*K
static constexpr int C2 = 256;    // C*D*D
static constexpr int OC = 64;     // outC
static constexpr int HWP  = H * W;    // 65536
static constexpr int HDWD = Hd * Wd;  // 16384

// ---------------- Kernel A: 1x1 down conv: x (N,64,H,W) fp32 -> k1 bf16 -----
__global__ __launch_bounds__(256) void kA_down(const float* __restrict__ x,
                                               const float* __restrict__ w,
                                               const float* __restrict__ b,
                                               bf16* __restrict__ k1) {
    __shared__ float wl[64 * 64];   // wl[c][cm]  (transposed for contiguous inner reads)
    const int tid = threadIdx.x;
    for (int i = tid; i < 64 * 64; i += 256) {
        int cm = i >> 6, c = i & 63;
        wl[c * 64 + cm] = w[i];     // w layout [cm][c]
    }
    __syncthreads();
    const int pix = blockIdx.x * 256 + tid;         // over N*H*W = 131072
    const int n  = pix >> 16;                       // / 65536
    const int hw = pix & (HWP - 1);
    const float* xb = x + (size_t)n * C * HWP + hw;
    float acc[64];
#pragma unroll
    for (int cm = 0; cm < 64; ++cm) acc[cm] = b[cm];
    for (int c = 0; c < 64; ++c) {
        float xv = xb[(size_t)c * HWP];
        const float* wr = &wl[c * 64];
#pragma unroll
        for (int cm = 0; cm < 64; ++cm) acc[cm] += xv * wr[cm];
    }
    bf16* kb = k1 + (size_t)n * Cm * HWP + hw;
#pragma unroll
    for (int cm = 0; cm < 64; ++cm) kb[(size_t)cm * HWP] = (bf16)acc[cm];
}

// -------- Kernel B: 3x3 s2 enc conv (64->25) + softmax -> ksm fp32 ----------
__global__ __launch_bounds__(256) void kB_enc(const bf16* __restrict__ k1,
                                              const float* __restrict__ ew,
                                              const float* __restrict__ eb,
                                              float* __restrict__ ksm) {
    __shared__ float wl[9 * 64 * 25];   // [tap][cm][kk] = 57.6 KB
    const int tid = threadIdx.x;
    for (int i = tid; i < 9 * 64 * 25; i += 256) {
        int tap = i / (64 * 25);
        int rem = i - tap * (64 * 25);
        int cm  = rem / 25;
        int kk  = rem - cm * 25;
        // ew layout: [kk][cm][3][3]
        wl[i] = ew[(kk * 64 + cm) * 9 + tap];
    }
    __syncthreads();
    const int pix = blockIdx.x * 256 + tid;   // over N*Hd*Wd = 32768
    const int n  = pix >> 14;
    const int hd = (pix >> 7) & 127;
    const int wd = pix & 127;
    float acc[25];
#pragma unroll
    for (int kk = 0; kk < 25; ++kk) acc[kk] = eb[kk];

    for (int dy = 0; dy < 3; ++dy) {
        int y = 2 * hd + dy - 1;
        if (y < 0 || y >= H) continue;
        for (int dx = 0; dx < 3; ++dx) {
            int xx = 2 * wd + dx - 1;
            if (xx < 0 || xx >= W) continue;
            const bf16* kbase = k1 + (size_t)n * Cm * HWP + y * W + xx;
            const float* wbase = &wl[(dy * 3 + dx) * 64 * 25];
            for (int cm = 0; cm < 64; ++cm) {
                float v = __bfloat162float(kbase[(size_t)cm * HWP]);
                const float* wr = wbase + cm * 25;
#pragma unroll
                for (int kk = 0; kk < 25; ++kk) acc[kk] += v * wr[kk];
            }
        }
    }
    // softmax over the 25 values
    float m = acc[0];
#pragma unroll
    for (int kk = 1; kk < 25; ++kk) m = fmaxf(m, acc[kk]);
    float s = 0.f;
#pragma unroll
    for (int kk = 0; kk < 25; ++kk) { acc[kk] = __expf(acc[kk] - m); s += acc[kk]; }
    float inv = 1.f / s;
    float* ob = ksm + (size_t)n * KK * HDWD + hd * Wd + wd;
#pragma unroll
    for (int kk = 0; kk < 25; ++kk) ob[(size_t)kk * HDWD] = acc[kk] * inv;
}

// ---- Kernel C: weighted reassembly -> out2 (N,256,Hd,Wd) bf16 --------------
__global__ __launch_bounds__(256) void kC_reassemble(const float* __restrict__ x,
                                                     const float* __restrict__ ksm,
                                                     bf16* __restrict__ out2) {
    const int idx = blockIdx.x * 256 + threadIdx.x;  // (n, c2, hd, wd) flat
    const int wd = idx & 127;
    const int hd = (idx >> 7) & 127;
    const int c2 = (idx >> 14) & 255;
    const int n  = idx >> 22;
    // inverse of the row-major reshape (C,H,W) -> (C*4, Hd, Wd):
    //   c2 = 4c + h/64,  hd = 2(h%64) + w/128,  wd = w%128
    const int c = c2 >> 2;
    const int h = (c2 & 3) * 64 + (hd >> 1);
    const int w = (hd & 1) * 128 + wd;
    const float* xb = x + (size_t)(n * C + c) * HWP;
    const float* kb = ksm + (size_t)n * KK * HDWD + hd * Wd + wd;
    float acc = 0.f;
#pragma unroll
    for (int i = 0; i < 5; ++i) {
        int y = h + i - 2;
        if (y < 0 || y >= H) continue;
#pragma unroll
        for (int j = 0; j < 5; ++j) {
            int xx = w + j - 2;
            if (xx < 0 || xx >= W) continue;
            acc += xb[y * W + xx] * kb[(size_t)(i * 5 + j) * HDWD];
        }
    }
    out2[idx] = (bf16)acc;
}

// ---- Kernel D: 1x1 out conv (256 -> 64) -> d_out (N,64,Hd,Wd) fp32 ---------
__global__ __launch_bounds__(256) void kD_out(const bf16* __restrict__ out2,
                                              const float* __restrict__ ow,
                                              const float* __restrict__ ob,
                                              float* __restrict__ out) {
    __shared__ float wl[256 * 64];   // [c2][co]  64 KB
    const int tid = threadIdx.x;
    for (int i = tid; i < 256 * 64; i += 256) {
        int co = i >> 8, c2 = i & 255;
        wl[c2 * 64 + co] = ow[i];     // ow layout [co][c2]
    }
    __syncthreads();
    const int pix = blockIdx.x * 256 + tid;   // over N*Hd*Wd = 32768
    const int n  = pix >> 14;
    const int hw = pix & (HDWD - 1);
    const bf16* ib = out2 + (size_t)n * C2 * HDWD + hw;
    float acc[64];
#pragma unroll
    for (int co = 0; co < 64; ++co) acc[co] = ob[co];
    for (int c2 = 0; c2 < 256; ++c2) {
        float v = __bfloat162float(ib[(size_t)c2 * HDWD]);
        const float* wr = &wl[c2 * 64];
#pragma unroll
        for (int co = 0; co < 64; ++co) acc[co] += v * wr[co];
    }
    float* outb = out + (size_t)n * OC * HDWD + hw;
#pragma unroll
    for (int co = 0; co < 64; ++co) outb[(size_t)co * HDWD] = acc[co];
}

extern "C" void kernel_launch(void* const* d_in, const int* in_sizes, int n_in,
                              void* d_out, int out_size, void* d_ws, size_t ws_size,
                              hipStream_t stream) {
    const float* x  = (const float*)d_in[0];
    const float* dw = (const float*)d_in[1];
    const float* db = (const float*)d_in[2];
    const float* ew = (const float*)d_in[3];
    const float* eb = (const float*)d_in[4];
    const float* ow = (const float*)d_in[5];
    const float* ob = (const float*)d_in[6];
    float* out = (float*)d_out;

    char* ws = (char*)d_ws;
    bf16*  k1   = (bf16*)ws;                                  // 2*64*65536*2  = 16,777,216 B
    float* ksm  = (float*)(ws + 16777216);                    // 2*25*16384*4  =  3,276,800 B
    bf16*  out2 = (bf16*)(ws + 16777216 + 3276800);           // 2*256*16384*2 = 16,777,216 B

    kA_down<<<dim3((N * HWP) / 256), dim3(256), 0, stream>>>(x, dw, db, k1);
    kB_enc<<<dim3((N * HDWD) / 256), dim3(256), 0, stream>>>(k1, ew, eb, ksm);
    kC_reassemble<<<dim3((N * C2 * HDWD) / 256), dim3(256), 0, stream>>>(x, ksm, out2);
    kD_out<<<dim3((N * HDWD) / 256), dim3(256), 0, stream>>>(out2, ow, ob, out);
}

// Round 3
// 271.783 us; speedup vs baseline: 1.3061x; 1.3061x over previous
//
#include <hip/hip_runtime.h>
#include <hip/hip_bf16.h>

using u16 = unsigned short;

static constexpr int N  = 2;
static constexpr int C  = 64;
static constexpr int H  = 256;
static constexpr int W  = 256;
static constexpr int Hd = 128;
static constexpr int Wd = 128;
static constexpr int Cm = 64;
static constexpr int KK = 25;
static constexpr int C2 = 256;
static constexpr int OC = 64;
static constexpr int HWP  = H * W;    // 65536
static constexpr int HDWD = Hd * Wd;  // 16384

__device__ __forceinline__ float bff(u16 u) {           // exact bf16 -> f32
    return __uint_as_float(((unsigned)u) << 16);
}
__device__ __forceinline__ unsigned pack2(float a, float b) {  // 2 x f32 -> packed bf16
    __hip_bfloat16 ha = __float2bfloat16(a), hb = __float2bfloat16(b);
    union { __hip_bfloat16 h; u16 u; } ua{ha}, ub{hb};
    return (unsigned)ua.u | ((unsigned)ub.u << 16);
}

// ---------------- Kernel A: 1x1 down conv (fp32 x -> bf16 k1) ---------------
// grid(64, 8): x = pixel chunk, y = cm group of 8. thread = 8 pixels x 8 cm.
__global__ __launch_bounds__(256) void kA_down(const float* __restrict__ x,
                                               const float* __restrict__ w,
                                               const float* __restrict__ b,
                                               u16* __restrict__ k1) {
    const int cm0 = blockIdx.y * 8;                      // block-uniform
    const int pg  = blockIdx.x * 256 + threadIdx.x;      // 0..16383
    const int n   = pg >> 13;
    const int hw  = (pg << 3) & (HWP - 1);
    const float* xb = x + (size_t)n * C * HWP + hw;

    float acc[8][8];
#pragma unroll
    for (int j = 0; j < 8; ++j) {
        float bj = b[cm0 + j];
#pragma unroll
        for (int p = 0; p < 8; ++p) acc[j][p] = bj;
    }
#pragma unroll 4
    for (int c = 0; c < 64; ++c) {
        const float* xp = xb + (size_t)c * HWP;
        float4 xa = *(const float4*)xp;
        float4 xc = *(const float4*)(xp + 4);
        float xs[8] = {xa.x, xa.y, xa.z, xa.w, xc.x, xc.y, xc.z, xc.w};
#pragma unroll
        for (int j = 0; j < 8; ++j) {
            float wv = w[(cm0 + j) * 64 + c];            // uniform -> s_load
#pragma unroll
            for (int p = 0; p < 8; ++p) acc[j][p] += wv * xs[p];
        }
    }
#pragma unroll
    for (int j = 0; j < 8; ++j) {
        uint4 o;
        o.x = pack2(acc[j][0], acc[j][1]);
        o.y = pack2(acc[j][2], acc[j][3]);
        o.z = pack2(acc[j][4], acc[j][5]);
        o.w = pack2(acc[j][6], acc[j][7]);
        *(uint4*)(k1 + (size_t)(n * Cm + cm0 + j) * HWP + hw) = o;
    }
}

// -------- Kernel B: 3x3 s2 enc conv (64->25) + softmax -> ksm fp32 ----------
// grid(512): block = 64 pixels (lanes) x 4 cm-quarters (waves).
__global__ __launch_bounds__(256) void kB_enc(const u16* __restrict__ k1,
                                              const float* __restrict__ ew,
                                              const float* __restrict__ eb,
                                              float* __restrict__ ksm) {
    __shared__ float red[4][64][28];
    const int tid  = threadIdx.x;
    const int lane = tid & 63;
    const int quarter = __builtin_amdgcn_readfirstlane(tid >> 6);
    const int pix = blockIdx.x * 64 + lane;
    const int n   = pix >> 14;
    const int hd  = (pix >> 7) & 127;
    const int wd  = pix & 127;
    const int cm0 = quarter * 16;

    float acc[25];
#pragma unroll
    for (int kk = 0; kk < 25; ++kk) acc[kk] = 0.f;

    for (int dy = 0; dy < 3; ++dy) {
        int y = 2 * hd + dy - 1;
        bool yok = (y >= 0) & (y < H);
        int yc = min(max(y, 0), H - 1);
        for (int dx = 0; dx < 3; ++dx) {
            int xx = 2 * wd + dx - 1;
            bool ok = yok & (xx >= 0) & (xx < W);
            int xc = min(max(xx, 0), W - 1);
            const int tap = dy * 3 + dx;
            const u16* kp = k1 + (size_t)(n * Cm) * HWP + yc * W + xc;
#pragma unroll 4
            for (int cm = cm0; cm < cm0 + 16; ++cm) {
                float v = bff(kp[(size_t)cm * HWP]);
                v = ok ? v : 0.f;
#pragma unroll
                for (int kk = 0; kk < 25; ++kk)
                    acc[kk] += v * ew[(kk * 64 + cm) * 9 + tap];  // uniform -> s_load
            }
        }
    }
#pragma unroll
    for (int kk = 0; kk < 25; ++kk) red[quarter][lane][kk] = acc[kk];
    __syncthreads();

    if (tid < 64) {
        float lg[25];
        float m = -1e30f;
#pragma unroll
        for (int kk = 0; kk < 25; ++kk) {
            float s = red[0][tid][kk] + red[1][tid][kk] + red[2][tid][kk]
                    + red[3][tid][kk] + eb[kk];
            lg[kk] = s;
            m = fmaxf(m, s);
        }
        float ssum = 0.f;
#pragma unroll
        for (int kk = 0; kk < 25; ++kk) { lg[kk] = __expf(lg[kk] - m); ssum += lg[kk]; }
        float inv = 1.f / ssum;
        float* ob = ksm + (size_t)n * KK * HDWD + hd * Wd + wd;
#pragma unroll
        for (int kk = 0; kk < 25; ++kk) ob[(size_t)kk * HDWD] = lg[kk] * inv;
    }
}

// ---- Kernel C: weighted reassembly -> out2 (N,256,Hd,Wd) bf16 --------------
// grid(512): b -> (n, q, hd-tile of 8, c-chunk of 16). thread = 4 wd outputs.
__global__ __launch_bounds__(256) void kC_reassemble(const float* __restrict__ x,
                                                     const float* __restrict__ ksm,
                                                     u16* __restrict__ out2) {
    __shared__ float xt[8][264];     // rows y0..y0+7, col w stored at slot w+2
    const int tid = threadIdx.x;
    const int cchunk = blockIdx.x & 3;
    const int hdt = (blockIdx.x >> 2) & 15;
    const int q   = (blockIdx.x >> 6) & 3;
    const int n   = blockIdx.x >> 8;
    const int hd0 = hdt * 8;
    const int hdo = tid >> 5;        // 0..7
    const int wdg = tid & 31;        // 0..31
    const int wd0 = wdg << 2;
    const int w0  = ((hdo & 1) << 7) + wd0;   // base image col of output group
    const int hd  = hd0 + hdo;
    const int lr0 = hdo >> 1;
    const int y0  = q * 64 + (hd0 >> 1) - 2;

    // softmax weights for this (hd, wd0..wd0+3): 25 x float4 in registers
    const float* kb = ksm + (size_t)n * KK * HDWD + hd * Wd + wd0;
    float4 kw[25];
#pragma unroll
    for (int kk = 0; kk < 25; ++kk) kw[kk] = *(const float4*)(kb + (size_t)kk * HDWD);

    const int srow = tid >> 5;       // staging row 0..7
    const int sseg = tid & 31;       // staging col segment (8 floats)
    const int c0 = cchunk * 16;

    for (int c = c0; c < c0 + 16; ++c) {
        __syncthreads();             // previous iteration's reads done
        const float* xc = x + (size_t)(n * C + c) * HWP;
        int y = y0 + srow;
        float* dst = &xt[srow][(sseg << 3) + 2];
        if (y >= 0 && y < H) {
            const float* rp = xc + y * W + (sseg << 3);
            float4 aa = *(const float4*)rp;
            float4 bb = *(const float4*)(rp + 4);
            *(float2*)(dst + 0) = make_float2(aa.x, aa.y);
            *(float2*)(dst + 2) = make_float2(aa.z, aa.w);
            *(float2*)(dst + 4) = make_float2(bb.x, bb.y);
            *(float2*)(dst + 6) = make_float2(bb.z, bb.w);
        } else {
            *(float2*)(dst + 0) = make_float2(0.f, 0.f);
            *(float2*)(dst + 2) = make_float2(0.f, 0.f);
            *(float2*)(dst + 4) = make_float2(0.f, 0.f);
            *(float2*)(dst + 6) = make_float2(0.f, 0.f);
        }
        if (tid < 8) {               // halo zeroing: cols -2,-1 and 256..259
            xt[tid][0] = 0.f; xt[tid][1] = 0.f;
            *(float4*)&xt[tid][258] = make_float4(0.f, 0.f, 0.f, 0.f);
        }
        __syncthreads();

        float a0 = 0.f, a1 = 0.f, a2 = 0.f, a3 = 0.f;
#pragma unroll
        for (int i = 0; i < 5; ++i) {
            const float* rr = &xt[lr0 + i][w0];   // slot w0 == col w0-2, 16B aligned
            float4 f0 = *(const float4*)rr;
            float4 f1 = *(const float4*)(rr + 4);
            float f[8] = {f0.x, f0.y, f0.z, f0.w, f1.x, f1.y, f1.z, f1.w};
#pragma unroll
            for (int j = 0; j < 5; ++j) {
                const float4 kv = kw[i * 5 + j];
                a0 += f[j + 0] * kv.x;
                a1 += f[j + 1] * kv.y;
                a2 += f[j + 2] * kv.z;
                a3 += f[j + 3] * kv.w;
            }
        }
        const int c2 = 4 * c + q;
        u16* op = out2 + ((size_t)(n * C2 + c2) * Hd + hd) * Wd + wd0;
        *(uint2*)op = make_uint2(pack2(a0, a1), pack2(a2, a3));
    }
}

// ---- Kernel D: 1x1 out conv (256 -> 64) -> d_out fp32 ----------------------
// grid(16, 16): x = pixel chunk, y = co group of 4. thread = 8 pixels x 4 co.
__global__ __launch_bounds__(256) void kD_out(const u16* __restrict__ out2,
                                              const float* __restrict__ ow,
                                              const float* __restrict__ ob,
                                              float* __restrict__ out) {
    const int co0 = blockIdx.y * 4;
    const int pg  = blockIdx.x * 256 + threadIdx.x;   // 0..4095
    const int n   = pg >> 11;
    const int hw  = (pg << 3) & (HDWD - 1);
    const u16* ib = out2 + (size_t)n * C2 * HDWD + hw;

    float acc[4][8];
#pragma unroll
    for (int j = 0; j < 4; ++j) {
        float bj = ob[co0 + j];
#pragma unroll
        for (int p = 0; p < 8; ++p) acc[j][p] = bj;
    }
#pragma unroll 4
    for (int c2 = 0; c2 < 256; ++c2) {
        uint4 u = *(const uint4*)(ib + (size_t)c2 * HDWD);
        float xs[8] = {bff((u16)(u.x & 0xffff)), bff((u16)(u.x >> 16)),
                       bff((u16)(u.y & 0xffff)), bff((u16)(u.y >> 16)),
                       bff((u16)(u.z & 0xffff)), bff((u16)(u.z >> 16)),
                       bff((u16)(u.w & 0xffff)), bff((u16)(u.w >> 16))};
#pragma unroll
        for (int j = 0; j < 4; ++j) {
            float wv = ow[(co0 + j) * 256 + c2];          // uniform -> s_load
#pragma unroll
            for (int p = 0; p < 8; ++p) acc[j][p] += wv * xs[p];
        }
    }
#pragma unroll
    for (int j = 0; j < 4; ++j) {
        float* op = out + (size_t)(n * OC + co0 + j) * HDWD + hw;
        *(float4*)(op + 0) = make_float4(acc[j][0], acc[j][1], acc[j][2], acc[j][3]);
        *(float4*)(op + 4) = make_float4(acc[j][4], acc[j][5], acc[j][6], acc[j][7]);
    }
}

extern "C" void kernel_launch(void* const* d_in, const int* in_sizes, int n_in,
                              void* d_out, int out_size, void* d_ws, size_t ws_size,
                              hipStream_t stream) {
    const float* x  = (const float*)d_in[0];
    const float* dw = (const float*)d_in[1];
    const float* db = (const float*)d_in[2];
    const float* ew = (const float*)d_in[3];
    const float* eb = (const float*)d_in[4];
    const float* ow = (const float*)d_in[5];
    const float* ob = (const float*)d_in[6];
    float* out = (float*)d_out;

    char* ws = (char*)d_ws;
    u16*   k1   = (u16*)ws;                               // 16,777,216 B
    float* ksm  = (float*)(ws + 16777216);                //  3,276,800 B
    u16*   out2 = (u16*)(ws + 16777216 + 3276800);        // 16,777,216 B

    kA_down<<<dim3(64, 8), dim3(256), 0, stream>>>(x, dw, db, k1);
    kB_enc<<<dim3(512), dim3(256), 0, stream>>>(k1, ew, eb, ksm);
    kC_reassemble<<<dim3(512), dim3(256), 0, stream>>>(x, ksm, out2);
    kD_out<<<dim3(16, 16), dim3(256), 0, stream>>>(out2, ow, ob, out);
}

// Round 4
// 202.057 us; speedup vs baseline: 1.7568x; 1.3451x over previous
//
#include <hip/hip_runtime.h>
#include <hip/hip_bf16.h>

using u16 = unsigned short;

static constexpr int N  = 2;
static constexpr int C  = 64;
static constexpr int H  = 256;
static constexpr int W  = 256;
static constexpr int Hd = 128;
static constexpr int Wd = 128;
static constexpr int Cm = 64;
static constexpr int KK = 25;
static constexpr int C2 = 256;
static constexpr int OC = 64;
static constexpr int HWP  = H * W;    // 65536
static constexpr int HDWD = Hd * Wd;  // 16384

__device__ __forceinline__ float bff(u16 u) {           // exact bf16 -> f32
    return __uint_as_float(((unsigned)u) << 16);
}
__device__ __forceinline__ unsigned pack2(float a, float b) {  // 2 x f32 -> packed bf16
    __hip_bfloat16 ha = __float2bfloat16(a), hb = __float2bfloat16(b);
    union { __hip_bfloat16 h; u16 u; } ua{ha}, ub{hb};
    return (unsigned)ua.u | ((unsigned)ub.u << 16);
}

// ---------------- Kernel A: 1x1 down conv (fp32 x -> bf16 k1) ---------------
__global__ __launch_bounds__(256) void kA_down(const float* __restrict__ x,
                                               const float* __restrict__ w,
                                               const float* __restrict__ b,
                                               u16* __restrict__ k1) {
    const int cm0 = blockIdx.y * 8;
    const int pg  = blockIdx.x * 256 + threadIdx.x;      // 0..16383
    const int n   = pg >> 13;
    const int hw  = (pg << 3) & (HWP - 1);
    const float* xb = x + (size_t)n * C * HWP + hw;

    float acc[8][8];
#pragma unroll
    for (int j = 0; j < 8; ++j) {
        float bj = b[cm0 + j];
#pragma unroll
        for (int p = 0; p < 8; ++p) acc[j][p] = bj;
    }
#pragma unroll 4
    for (int c = 0; c < 64; ++c) {
        const float* xp = xb + (size_t)c * HWP;
        float4 xa = *(const float4*)xp;
        float4 xc = *(const float4*)(xp + 4);
        float xs[8] = {xa.x, xa.y, xa.z, xa.w, xc.x, xc.y, xc.z, xc.w};
#pragma unroll
        for (int j = 0; j < 8; ++j) {
            float wv = w[(cm0 + j) * 64 + c];            // uniform -> s_load
#pragma unroll
            for (int p = 0; p < 8; ++p) acc[j][p] += wv * xs[p];
        }
    }
#pragma unroll
    for (int j = 0; j < 8; ++j) {
        uint4 o;
        o.x = pack2(acc[j][0], acc[j][1]);
        o.y = pack2(acc[j][2], acc[j][3]);
        o.z = pack2(acc[j][4], acc[j][5]);
        o.w = pack2(acc[j][6], acc[j][7]);
        *(uint4*)(k1 + (size_t)(n * Cm + cm0 + j) * HWP + hw) = o;
    }
}

// ---- Kernel W: repack enc weights  ew[kk][cm][3][3] -> ewt[tap][cm][kk] ----
__global__ __launch_bounds__(256) void kW_repack(const float* __restrict__ ew,
                                                 float* __restrict__ ewt) {
    int i = blockIdx.x * 256 + threadIdx.x;   // over 25*64*9 = 14400
    if (i < 25 * 64 * 9) {
        int tap = i % 9;
        int r   = i / 9;
        int cm  = r % 64;
        int kk  = r / 64;
        ewt[(tap * 64 + cm) * 25 + kk] = ew[i];
    }
}

// -------- Kernel B: 3x3 s2 enc conv (64->25) + softmax -> ksm fp32 ----------
// grid(512): block = 64 pixels (lanes, one hd row) x 4 cm-quarters (waves).
__global__ __launch_bounds__(256) void kB_enc(const u16* __restrict__ k1,
                                              const float* __restrict__ ewt,
                                              const float* __restrict__ eb,
                                              float* __restrict__ ksm) {
    __shared__ float red[4][64][28];
    const int tid  = threadIdx.x;
    const int lane = tid & 63;
    const int quarter = __builtin_amdgcn_readfirstlane(tid >> 6);
    const int pix = blockIdx.x * 64 + lane;
    const int n   = pix >> 14;
    const int hd  = (pix >> 7) & 127;      // wave-uniform
    const int wd  = pix & 127;             // per-lane
    const int cm0 = quarter * 16;

    float acc[25];
#pragma unroll
    for (int kk = 0; kk < 25; ++kk) acc[kk] = 0.f;

    const u16* kbase = k1 + (size_t)(n * Cm) * HWP;

    for (int dy = 0; dy < 3; ++dy) {
        int y = 2 * hd + dy - 1;
        if (y < 0 || y >= H) continue;     // uniform branch (hd uniform per wave)
        for (int dx = 0; dx < 3; ++dx) {
            int xx = 2 * wd + dx - 1;      // only xx<0 possible (lane 0, dx 0)
            bool ok = (xx >= 0);
            int xc = max(xx, 0);
            const int tap = dy * 3 + dx;
            const u16* kp = kbase + y * W + xc;
            float v[16];
#pragma unroll
            for (int i = 0; i < 16; ++i) v[i] = bff(kp[(size_t)(cm0 + i) * HWP]);
            if (!ok) {
#pragma unroll
                for (int i = 0; i < 16; ++i) v[i] = 0.f;
            }
            const float* wp = ewt + (tap * 64 + cm0) * 25;   // uniform, contiguous
#pragma unroll
            for (int i = 0; i < 16; ++i) {
#pragma unroll
                for (int kk = 0; kk < 25; ++kk)
                    acc[kk] = fmaf(v[i], wp[i * 25 + kk], acc[kk]);
            }
        }
    }
#pragma unroll
    for (int kk = 0; kk < 25; ++kk) red[quarter][lane][kk] = acc[kk];
    __syncthreads();

    if (tid < 64) {
        float lg[25];
        float m = -1e30f;
#pragma unroll
        for (int kk = 0; kk < 25; ++kk) {
            float s = red[0][tid][kk] + red[1][tid][kk] + red[2][tid][kk]
                    + red[3][tid][kk] + eb[kk];
            lg[kk] = s;
            m = fmaxf(m, s);
        }
        float ssum = 0.f;
#pragma unroll
        for (int kk = 0; kk < 25; ++kk) { lg[kk] = __expf(lg[kk] - m); ssum += lg[kk]; }
        float inv = 1.f / ssum;
        float* ob = ksm + (size_t)n * KK * HDWD + hd * Wd + wd;
#pragma unroll
        for (int kk = 0; kk < 25; ++kk) ob[(size_t)kk * HDWD] = lg[kk] * inv;
    }
}

// ---- Kernel C: weighted reassembly -> out2 (N,256,Hd,Wd) bf16 --------------
__global__ __launch_bounds__(256) void kC_reassemble(const float* __restrict__ x,
                                                     const float* __restrict__ ksm,
                                                     u16* __restrict__ out2) {
    __shared__ float xt[8][264];     // rows y0..y0+7, col w stored at slot w+2
    const int tid = threadIdx.x;
    const int cchunk = blockIdx.x & 3;
    const int hdt = (blockIdx.x >> 2) & 15;
    const int q   = (blockIdx.x >> 6) & 3;
    const int n   = blockIdx.x >> 8;
    const int hd0 = hdt * 8;
    const int hdo = tid >> 5;        // 0..7
    const int wdg = tid & 31;        // 0..31
    const int wd0 = wdg << 2;
    const int w0  = ((hdo & 1) << 7) + wd0;
    const int hd  = hd0 + hdo;
    const int lr0 = hdo >> 1;
    const int y0  = q * 64 + (hd0 >> 1) - 2;

    const float* kb = ksm + (size_t)n * KK * HDWD + hd * Wd + wd0;
    float4 kw[25];
#pragma unroll
    for (int kk = 0; kk < 25; ++kk) kw[kk] = *(const float4*)(kb + (size_t)kk * HDWD);

    const int srow = tid >> 5;
    const int sseg = tid & 31;
    const int c0 = cchunk * 16;

    for (int c = c0; c < c0 + 16; ++c) {
        __syncthreads();
        const float* xc = x + (size_t)(n * C + c) * HWP;
        int y = y0 + srow;
        float* dst = &xt[srow][(sseg << 3) + 2];
        if (y >= 0 && y < H) {
            const float* rp = xc + y * W + (sseg << 3);
            float4 aa = *(const float4*)rp;
            float4 bb = *(const float4*)(rp + 4);
            *(float2*)(dst + 0) = make_float2(aa.x, aa.y);
            *(float2*)(dst + 2) = make_float2(aa.z, aa.w);
            *(float2*)(dst + 4) = make_float2(bb.x, bb.y);
            *(float2*)(dst + 6) = make_float2(bb.z, bb.w);
        } else {
            *(float2*)(dst + 0) = make_float2(0.f, 0.f);
            *(float2*)(dst + 2) = make_float2(0.f, 0.f);
            *(float2*)(dst + 4) = make_float2(0.f, 0.f);
            *(float2*)(dst + 6) = make_float2(0.f, 0.f);
        }
        if (tid < 8) {
            xt[tid][0] = 0.f; xt[tid][1] = 0.f;
            *(float4*)&xt[tid][258] = make_float4(0.f, 0.f, 0.f, 0.f);
        }
        __syncthreads();

        float a0 = 0.f, a1 = 0.f, a2 = 0.f, a3 = 0.f;
#pragma unroll
        for (int i = 0; i < 5; ++i) {
            const float* rr = &xt[lr0 + i][w0];
            float4 f0 = *(const float4*)rr;
            float4 f1 = *(const float4*)(rr + 4);
            float f[8] = {f0.x, f0.y, f0.z, f0.w, f1.x, f1.y, f1.z, f1.w};
#pragma unroll
            for (int j = 0; j < 5; ++j) {
                const float4 kv = kw[i * 5 + j];
                a0 += f[j + 0] * kv.x;
                a1 += f[j + 1] * kv.y;
                a2 += f[j + 2] * kv.z;
                a3 += f[j + 3] * kv.w;
            }
        }
        const int c2 = 4 * c + q;
        u16* op = out2 + ((size_t)(n * C2 + c2) * Hd + hd) * Wd + wd0;
        *(uint2*)op = make_uint2(pack2(a0, a1), pack2(a2, a3));
    }
}

// ---- Kernel D: 1x1 out conv (256 -> 64) -> d_out fp32 ----------------------
__global__ __launch_bounds__(256) void kD_out(const u16* __restrict__ out2,
                                              const float* __restrict__ ow,
                                              const float* __restrict__ ob,
                                              float* __restrict__ out) {
    const int co0 = blockIdx.y * 4;
    const int pg  = blockIdx.x * 256 + threadIdx.x;   // 0..4095
    const int n   = pg >> 11;
    const int hw  = (pg << 3) & (HDWD - 1);
    const u16* ib = out2 + (size_t)n * C2 * HDWD + hw;

    float acc[4][8];
#pragma unroll
    for (int j = 0; j < 4; ++j) {
        float bj = ob[co0 + j];
#pragma unroll
        for (int p = 0; p < 8; ++p) acc[j][p] = bj;
    }
#pragma unroll 4
    for (int c2 = 0; c2 < 256; ++c2) {
        uint4 u = *(const uint4*)(ib + (size_t)c2 * HDWD);
        float xs[8] = {bff((u16)(u.x & 0xffff)), bff((u16)(u.x >> 16)),
                       bff((u16)(u.y & 0xffff)), bff((u16)(u.y >> 16)),
                       bff((u16)(u.z & 0xffff)), bff((u16)(u.z >> 16)),
                       bff((u16)(u.w & 0xffff)), bff((u16)(u.w >> 16))};
#pragma unroll
        for (int j = 0; j < 4; ++j) {
            float wv = ow[(co0 + j) * 256 + c2];          // uniform -> s_load
#pragma unroll
            for (int p = 0; p < 8; ++p) acc[j][p] += wv * xs[p];
        }
    }
#pragma unroll
    for (int j = 0; j < 4; ++j) {
        float* op = out + (size_t)(n * OC + co0 + j) * HDWD + hw;
        *(float4*)(op + 0) = make_float4(acc[j][0], acc[j][1], acc[j][2], acc[j][3]);
        *(float4*)(op + 4) = make_float4(acc[j][4], acc[j][5], acc[j][6], acc[j][7]);
    }
}

extern "C" void kernel_launch(void* const* d_in, const int* in_sizes, int n_in,
                              void* d_out, int out_size, void* d_ws, size_t ws_size,
                              hipStream_t stream) {
    const float* x  = (const float*)d_in[0];
    const float* dw = (const float*)d_in[1];
    const float* db = (const float*)d_in[2];
    const float* ew = (const float*)d_in[3];
    const float* eb = (const float*)d_in[4];
    const float* ow = (const float*)d_in[5];
    const float* ob = (const float*)d_in[6];
    float* out = (float*)d_out;

    char* ws = (char*)d_ws;
    u16*   k1   = (u16*)ws;                               // 16,777,216 B
    float* ksm  = (float*)(ws + 16777216);                //  3,276,800 B
    u16*   out2 = (u16*)(ws + 16777216 + 3276800);        // 16,777,216 B
    // ewt (57.6 KB) overlaps the head of out2: kW writes it, kB reads it,
    // kC clobbers it afterwards (stream-ordered, safe).
    float* ewt  = (float*)out2;

    kA_down<<<dim3(64, 8), dim3(256), 0, stream>>>(x, dw, db, k1);
    kW_repack<<<dim3(57), dim3(256), 0, stream>>>(ew, ewt);
    kB_enc<<<dim3(512), dim3(256), 0, stream>>>(k1, ewt, eb, ksm);
    kC_reassemble<<<dim3(512), dim3(256), 0, stream>>>(x, ksm, out2);
    kD_out<<<dim3(16, 16), dim3(256), 0, stream>>>(out2, ow, ob, out);
}

// Round 5
// 182.972 us; speedup vs baseline: 1.9400x; 1.1043x over previous
//
#include <hip/hip_runtime.h>
#include <hip/hip_bf16.h>

using u16 = unsigned short;

static constexpr int N  = 2;
static constexpr int C  = 64;
static constexpr int H  = 256;
static constexpr int W  = 256;
static constexpr int Hd = 128;
static constexpr int Wd = 128;
static constexpr int Cm = 64;
static constexpr int KK = 25;
static constexpr int C2 = 256;
static constexpr int OC = 64;
static constexpr int HWP  = H * W;    // 65536
static constexpr int HDWD = Hd * Wd;  // 16384

__device__ __forceinline__ float bff(u16 u) {           // exact bf16 -> f32
    return __uint_as_float(((unsigned)u) << 16);
}
__device__ __forceinline__ float bflo(unsigned u) { return __uint_as_float(u << 16); }
__device__ __forceinline__ float bfhi(unsigned u) { return __uint_as_float(u & 0xffff0000u); }
__device__ __forceinline__ unsigned pack2(float a, float b) {  // 2 x f32 -> packed bf16
    __hip_bfloat16 ha = __float2bfloat16(a), hb = __float2bfloat16(b);
    union { __hip_bfloat16 h; u16 u; } ua{ha}, ub{hb};
    return (unsigned)ua.u | ((unsigned)ub.u << 16);
}

// ---------------- Kernel A: 1x1 down conv -> k1 PIXEL-MAJOR [n][px][cm] -----
// grid(512): block = 256 flat pixels x all 64 cm. LDS-staged x (bf16) + w.
__global__ __launch_bounds__(256) void kA_down(const float* __restrict__ x,
                                               const float* __restrict__ w,
                                               const float* __restrict__ b,
                                               u16* __restrict__ k1) {
    __shared__ u16   xt[64][256];    // bf16 x tile [c][px_local]   32 KB
    __shared__ float wt[64][66];     // w transposed [c][cm], pad 66  16.9 KB
    const int tid = threadIdx.x;
    const int pg0 = blockIdx.x * 256;          // flat pixel base over N*HWP
    const int n   = pg0 >> 16;
    const int px0 = pg0 & (HWP - 1);

    // stage weights: w[cm][c] -> wt[c][cm]  (conflict-free: bank = (2c+cm)%32)
#pragma unroll
    for (int i = 0; i < 16; ++i) {
        int e  = i * 256 + tid;                // 0..4095
        int cm = e >> 6, c = e & 63;
        wt[c][cm] = w[e];
    }
    // stage x tile as bf16 (coalesced 1KB/wave global, contiguous LDS writes)
    const float* xb = x + (size_t)n * C * HWP + px0;
#pragma unroll
    for (int i = 0; i < 16; ++i) {
        int flat = i * 256 + tid;              // float4 index 0..4095
        int row  = flat >> 6;                  // channel c
        int col4 = flat & 63;                  // float4 within row
        float4 v = *(const float4*)(xb + (size_t)row * HWP + col4 * 4);
        uint2 p;
        p.x = pack2(v.x, v.y);
        p.y = pack2(v.z, v.w);
        *(uint2*)&xt[row][col4 * 4] = p;
    }
    __syncthreads();

    const int cg  = tid & 7;                   // cm group (8 cm)
    const int pxg = tid >> 3;                  // pixel group (8 px)
    float acc[8][8];                           // [cm][px]
#pragma unroll
    for (int j = 0; j < 8; ++j) {
        float bj = b[cg * 8 + j];
#pragma unroll
        for (int p = 0; p < 8; ++p) acc[j][p] = bj;
    }
#pragma unroll 8
    for (int c = 0; c < 64; ++c) {
        uint4 xv = *(const uint4*)&xt[c][pxg * 8];     // 8 bf16 px
        float xs[8] = {bflo(xv.x), bfhi(xv.x), bflo(xv.y), bfhi(xv.y),
                       bflo(xv.z), bfhi(xv.z), bflo(xv.w), bfhi(xv.w)};
        float2 w01 = *(const float2*)&wt[c][cg * 8 + 0];
        float2 w23 = *(const float2*)&wt[c][cg * 8 + 2];
        float2 w45 = *(const float2*)&wt[c][cg * 8 + 4];
        float2 w67 = *(const float2*)&wt[c][cg * 8 + 6];
        float wv[8] = {w01.x, w01.y, w23.x, w23.y, w45.x, w45.y, w67.x, w67.y};
#pragma unroll
        for (int j = 0; j < 8; ++j)
#pragma unroll
            for (int p = 0; p < 8; ++p) acc[j][p] = fmaf(wv[j], xs[p], acc[j][p]);
    }
    // write pixel-major: per px, 8 contiguous cm bf16 = 16B
#pragma unroll
    for (int p = 0; p < 8; ++p) {
        uint4 o;
        o.x = pack2(acc[0][p], acc[1][p]);
        o.y = pack2(acc[2][p], acc[3][p]);
        o.z = pack2(acc[4][p], acc[5][p]);
        o.w = pack2(acc[6][p], acc[7][p]);
        *(uint4*)(k1 + ((size_t)pg0 + pxg * 8 + p) * 64 + cg * 8) = o;
    }
}

// ---- Kernel W: repack enc weights  ew[kk][cm][3][3] -> ewt[tap][cm][kk] ----
__global__ __launch_bounds__(256) void kW_repack(const float* __restrict__ ew,
                                                 float* __restrict__ ewt) {
    int i = blockIdx.x * 256 + threadIdx.x;   // over 25*64*9 = 14400
    if (i < 25 * 64 * 9) {
        int tap = i % 9;
        int r   = i / 9;
        int cm  = r % 64;
        int kk  = r / 64;
        ewt[(tap * 64 + cm) * 25 + kk] = ew[i];
    }
}

// -------- Kernel B: 3x3 s2 enc conv (64->25) + softmax -> ksm fp32 ----------
// grid(512): block = 64 pixels (lanes, one hd row) x 4 cm-quarters (waves).
// k1 is pixel-major: 16 cm per tap = 2 x dwordx4.
__global__ __launch_bounds__(256) void kB_enc(const u16* __restrict__ k1,
                                              const float* __restrict__ ewt,
                                              const float* __restrict__ eb,
                                              float* __restrict__ ksm) {
    __shared__ float red[4][64][29];
    const int tid  = threadIdx.x;
    const int lane = tid & 63;
    const int quarter = __builtin_amdgcn_readfirstlane(tid >> 6);
    const int pix = blockIdx.x * 64 + lane;
    const int n   = pix >> 14;
    const int hd  = (pix >> 7) & 127;      // wave-uniform
    const int wd  = pix & 127;             // per-lane
    const int cm0 = quarter * 16;

    float acc[25];
#pragma unroll
    for (int kk = 0; kk < 25; ++kk) acc[kk] = 0.f;

    const u16* kbase = k1 + (size_t)n * HWP * 64;

    for (int dy = 0; dy < 3; ++dy) {
        int y = 2 * hd + dy - 1;
        if (y < 0 || y >= H) continue;     // uniform branch
        for (int dx = 0; dx < 3; ++dx) {
            int xx = 2 * wd + dx - 1;      // only xx<0 possible at border
            bool ok = (xx >= 0);
            int xc = max(xx, 0);
            const int tap = dy * 3 + dx;
            const u16* kp = kbase + ((size_t)y * W + xc) * 64 + cm0;
            uint4 a = *(const uint4*)kp;
            uint4 bq = *(const uint4*)(kp + 8);
            float v[16] = {bflo(a.x),  bfhi(a.x),  bflo(a.y),  bfhi(a.y),
                           bflo(a.z),  bfhi(a.z),  bflo(a.w),  bfhi(a.w),
                           bflo(bq.x), bfhi(bq.x), bflo(bq.y), bfhi(bq.y),
                           bflo(bq.z), bfhi(bq.z), bflo(bq.w), bfhi(bq.w)};
            if (!ok) {
#pragma unroll
                for (int i = 0; i < 16; ++i) v[i] = 0.f;
            }
            const float* wp = ewt + (tap * 64 + cm0) * 25;   // uniform s_loads
#pragma unroll
            for (int i = 0; i < 16; ++i)
#pragma unroll
                for (int kk = 0; kk < 25; ++kk)
                    acc[kk] = fmaf(v[i], wp[i * 25 + kk], acc[kk]);
        }
    }
#pragma unroll
    for (int kk = 0; kk < 25; ++kk) red[quarter][lane][kk] = acc[kk];
    __syncthreads();

    if (tid < 64) {
        float lg[25];
        float m = -1e30f;
#pragma unroll
        for (int kk = 0; kk < 25; ++kk) {
            float s = red[0][tid][kk] + red[1][tid][kk] + red[2][tid][kk]
                    + red[3][tid][kk] + eb[kk];
            lg[kk] = s;
            m = fmaxf(m, s);
        }
        float ssum = 0.f;
#pragma unroll
        for (int kk = 0; kk < 25; ++kk) { lg[kk] = __expf(lg[kk] - m); ssum += lg[kk]; }
        float inv = 1.f / ssum;
        float* ob = ksm + (size_t)n * KK * HDWD + hd * Wd + wd;
#pragma unroll
        for (int kk = 0; kk < 25; ++kk) ob[(size_t)kk * HDWD] = lg[kk] * inv;
    }
}

// ---- Kernel C: weighted reassembly -> out2 (N,256,Hd,Wd) bf16 --------------
// Software-pipelined: prefetch channel c+1 while computing c.
__global__ __launch_bounds__(256) void kC_reassemble(const float* __restrict__ x,
                                                     const float* __restrict__ ksm,
                                                     u16* __restrict__ out2) {
    __shared__ float xt[8][264];     // rows y0..y0+7, col w at slot w+2
    const int tid = threadIdx.x;
    const int cchunk = blockIdx.x & 3;
    const int hdt = (blockIdx.x >> 2) & 15;
    const int q   = (blockIdx.x >> 6) & 3;
    const int n   = blockIdx.x >> 8;
    const int hd0 = hdt * 8;
    const int hdo = tid >> 5;        // 0..7
    const int wdg = tid & 31;        // 0..31
    const int wd0 = wdg << 2;
    const int w0  = ((hdo & 1) << 7) + wd0;
    const int hd  = hd0 + hdo;
    const int lr0 = hdo >> 1;
    const int y0  = q * 64 + (hd0 >> 1) - 2;

    const float* kb = ksm + (size_t)n * KK * HDWD + hd * Wd + wd0;
    float4 kw[25];
#pragma unroll
    for (int kk = 0; kk < 25; ++kk) kw[kk] = *(const float4*)(kb + (size_t)kk * HDWD);

    const int srow = tid >> 5;
    const int sseg = tid & 31;
    const int c0 = cchunk * 16;

    const int y = y0 + srow;
    const bool yin = (y >= 0 && y < H);
    const float* rp0 = x + (size_t)n * C * HWP + y * W + (sseg << 3);

    float4 pa, pb;
    if (yin) {
        pa = *(const float4*)(rp0 + (size_t)c0 * HWP);
        pb = *(const float4*)(rp0 + (size_t)c0 * HWP + 4);
    } else {
        pa = make_float4(0.f, 0.f, 0.f, 0.f);
        pb = pa;
    }

    for (int c = c0; c < c0 + 16; ++c) {
        __syncthreads();             // previous iteration's reads done
        float* dst = &xt[srow][(sseg << 3) + 2];
        *(float2*)(dst + 0) = make_float2(pa.x, pa.y);
        *(float2*)(dst + 2) = make_float2(pa.z, pa.w);
        *(float2*)(dst + 4) = make_float2(pb.x, pb.y);
        *(float2*)(dst + 6) = make_float2(pb.z, pb.w);
        if (tid < 8) {               // halo zeroing
            xt[tid][0] = 0.f; xt[tid][1] = 0.f;
            *(float4*)&xt[tid][258] = make_float4(0.f, 0.f, 0.f, 0.f);
        }
        __syncthreads();

        if (c + 1 < c0 + 16 && yin) {        // prefetch next channel
            pa = *(const float4*)(rp0 + (size_t)(c + 1) * HWP);
            pb = *(const float4*)(rp0 + (size_t)(c + 1) * HWP + 4);
        }

        float a0 = 0.f, a1 = 0.f, a2 = 0.f, a3 = 0.f;
#pragma unroll
        for (int i = 0; i < 5; ++i) {
            const float* rr = &xt[lr0 + i][w0];
            float4 f0 = *(const float4*)rr;
            float4 f1 = *(const float4*)(rr + 4);
            float f[8] = {f0.x, f0.y, f0.z, f0.w, f1.x, f1.y, f1.z, f1.w};
#pragma unroll
            for (int j = 0; j < 5; ++j) {
                const float4 kv = kw[i * 5 + j];
                a0 += f[j + 0] * kv.x;
                a1 += f[j + 1] * kv.y;
                a2 += f[j + 2] * kv.z;
                a3 += f[j + 3] * kv.w;
            }
        }
        const int c2 = 4 * c + q;
        u16* op = out2 + ((size_t)(n * C2 + c2) * Hd + hd) * Wd + wd0;
        *(uint2*)op = make_uint2(pack2(a0, a1), pack2(a2, a3));
    }
}

// ---- Kernel D: 1x1 out conv (256 -> 64) -> d_out fp32 ----------------------
// grid(32,16): thread = 4 px x 4 co; c2-loop with 8-deep load batches.
__global__ __launch_bounds__(256) void kD_out(const u16* __restrict__ out2,
                                              const float* __restrict__ ow,
                                              const float* __restrict__ ob,
                                              float* __restrict__ out) {
    const int co0 = blockIdx.y * 4;
    const int pg  = blockIdx.x * 256 + threadIdx.x;   // 0..8191
    const int n   = pg >> 12;
    const int hw  = (pg << 2) & (HDWD - 1);
    const u16* ib = out2 + (size_t)n * C2 * HDWD + hw;

    float acc[4][4];
#pragma unroll
    for (int j = 0; j < 4; ++j) {
        float bj = ob[co0 + j];
#pragma unroll
        for (int p = 0; p < 4; ++p) acc[j][p] = bj;
    }
    for (int c2 = 0; c2 < 256; c2 += 8) {
        uint2 u[8];
#pragma unroll
        for (int t = 0; t < 8; ++t)
            u[t] = *(const uint2*)(ib + (size_t)(c2 + t) * HDWD);
#pragma unroll
        for (int t = 0; t < 8; ++t) {
            float xs[4] = {bflo(u[t].x), bfhi(u[t].x), bflo(u[t].y), bfhi(u[t].y)};
#pragma unroll
            for (int j = 0; j < 4; ++j) {
                float wv = ow[(co0 + j) * 256 + c2 + t];   // uniform -> s_load
#pragma unroll
                for (int p = 0; p < 4; ++p) acc[j][p] = fmaf(wv, xs[p], acc[j][p]);
            }
        }
    }
#pragma unroll
    for (int j = 0; j < 4; ++j) {
        float* op = out + (size_t)(n * OC + co0 + j) * HDWD + hw;
        *(float4*)op = make_float4(acc[j][0], acc[j][1], acc[j][2], acc[j][3]);
    }
}

extern "C" void kernel_launch(void* const* d_in, const int* in_sizes, int n_in,
                              void* d_out, int out_size, void* d_ws, size_t ws_size,
                              hipStream_t stream) {
    const float* x  = (const float*)d_in[0];
    const float* dw = (const float*)d_in[1];
    const float* db = (const float*)d_in[2];
    const float* ew = (const float*)d_in[3];
    const float* eb = (const float*)d_in[4];
    const float* ow = (const float*)d_in[5];
    const float* ob = (const float*)d_in[6];
    float* out = (float*)d_out;

    char* ws = (char*)d_ws;
    u16*   k1   = (u16*)ws;                               // 16,777,216 B  [n][px][cm]
    float* ksm  = (float*)(ws + 16777216);                //  3,276,800 B
    u16*   out2 = (u16*)(ws + 16777216 + 3276800);        // 16,777,216 B
    // ewt (57.6 KB) overlaps out2's head: kW writes, kB reads, kC clobbers after.
    float* ewt  = (float*)out2;

    kA_down<<<dim3(512), dim3(256), 0, stream>>>(x, dw, db, k1);
    kW_repack<<<dim3(57), dim3(256), 0, stream>>>(ew, ewt);
    kB_enc<<<dim3(512), dim3(256), 0, stream>>>(k1, ewt, eb, ksm);
    kC_reassemble<<<dim3(512), dim3(256), 0, stream>>>(x, ksm, out2);
    kD_out<<<dim3(32, 16), dim3(256), 0, stream>>>(out2, ow, ob, out);
}